// Round 10
// baseline (190.356 us; speedup 1.0000x reference)
//
#include <hip/hip_runtime.h>
#include <hip/hip_bf16.h>

#define NDIM   512
#define NPOS   1024   // 32*32
#define NB     8
#define INNER  1536
#define DHEAD  64

typedef __attribute__((ext_vector_type(8))) short bf8v;   // 8 bf16 = 4 VGPRs
typedef __attribute__((ext_vector_type(4))) float f4v;

__device__ __forceinline__ f4v mfma16(bf8v a, bf8v b, f4v c) {
    return __builtin_amdgcn_mfma_f32_16x16x32_bf16(a, b, c, 0, 0, 0);
}

__device__ __forceinline__ unsigned short f2bs(float v) {
    __hip_bfloat16 h = __float2bfloat16(v);   // RNE
    return *reinterpret_cast<unsigned short*>(&h);
}

// async global->LDS, 16B per lane; lds dst = wave-uniform base + lane*16
__device__ __forceinline__ void gl_lds16(const unsigned short* g, unsigned short* l) {
    __builtin_amdgcn_global_load_lds(
        (const __attribute__((address_space(1))) void*)g,
        (__attribute__((address_space(3))) void*)l,
        16, 0, 0);
}

// ---------------- K1: fused LN stats + normalize + cast + transpose -------
__global__ __launch_bounds__(256) void ln_xnorm_kernel(
    const float* __restrict__ x, const float* __restrict__ gamma,
    unsigned short* __restrict__ xnT)
{
    __shared__ float ssum[4][64];
    __shared__ float ssq[4][64];
    __shared__ float mean_s[64];
    __shared__ float rstd_s[64];
    __shared__ unsigned short tile[64][72];

    const int b = blockIdx.y;
    const int n0 = blockIdx.x * 64;
    const int t = threadIdx.x;

    {
        const int ln = t & 63, cg = t >> 6;
        const float* xp = x + (size_t)b * NDIM * NPOS + n0 + ln;
        float s = 0.f, ss = 0.f;
        for (int c = cg * 128; c < cg * 128 + 128; ++c) {
            float v = xp[(size_t)c * NPOS];
            s += v; ss += v * v;
        }
        ssum[cg][ln] = s; ssq[cg][ln] = ss;
    }
    __syncthreads();
    if (t < 64) {
        float st = ssum[0][t] + ssum[1][t] + ssum[2][t] + ssum[3][t];
        float sq = ssq[0][t] + ssq[1][t] + ssq[2][t] + ssq[3][t];
        float m = st * (1.0f / NDIM);
        float var = sq * (1.0f / NDIM) - m * m;
        mean_s[t] = m;
        rstd_s[t] = rsqrtf(var + 1e-5f);
    }
    __syncthreads();

    const int cl = t >> 2, nq = (t & 3) * 16;
    const int n = t >> 2, cq = (t & 3) * 16;
    for (int c0 = 0; c0 < NDIM; c0 += 64) {
        const float g = gamma[c0 + cl];
        const float* xp = x + ((size_t)b * NDIM + c0 + cl) * NPOS + n0 + nq;
#pragma unroll
        for (int q = 0; q < 4; ++q) {
            float4 v = *(const float4*)(xp + q * 4);
            float4 m = *(const float4*)&mean_s[nq + q * 4];
            float4 r = *(const float4*)&rstd_s[nq + q * 4];
            tile[nq + q * 4 + 0][cl] = f2bs((v.x - m.x) * r.x * g);
            tile[nq + q * 4 + 1][cl] = f2bs((v.y - m.y) * r.y * g);
            tile[nq + q * 4 + 2][cl] = f2bs((v.z - m.z) * r.z * g);
            tile[nq + q * 4 + 3][cl] = f2bs((v.w - m.w) * r.w * g);
        }
        __syncthreads();
        unsigned short* dst = xnT + ((size_t)b * NPOS + n0 + n) * NDIM + c0 + cq;
        *(uint4*)dst       = *(const uint4*)&tile[n][cq];
        *(uint4*)(dst + 8) = *(const uint4*)&tile[n][cq + 8];
        __syncthreads();
    }
}

// ---------------- K1b: f32 -> bf16 cast, both weights in one grid ---------
__global__ __launch_bounds__(256) void castw2_kernel(
    const float* __restrict__ wq, unsigned short* __restrict__ wqb,
    const float* __restrict__ wo, unsigned short* __restrict__ wob)
{
    const int n1 = INNER * NDIM / 4;
    int i = blockIdx.x * 256 + threadIdx.x;
    const float* src; unsigned short* dst; int j;
    if (i < n1) { src = wq; dst = wqb; j = i; }
    else        { src = wo; dst = wob; j = i - n1; }
    float4 v = ((const float4*)src)[j];
    ushort4 u;
    u.x = f2bs(v.x); u.y = f2bs(v.y); u.z = f2bs(v.z); u.w = f2bs(v.w);
    ((ushort4*)dst)[j] = u;
}

// ---------------- K2: QKV GEMM (MFMA bf16, async LDS staging) -------------
__global__ __launch_bounds__(256) void qkv_mfma_kernel(
    const unsigned short* __restrict__ wq, const unsigned short* __restrict__ xnT,
    unsigned short* __restrict__ qT, unsigned short* __restrict__ kT,
    unsigned short* __restrict__ vv)
{
    __shared__ __align__(16) unsigned short smem[4 * 64 * 72];  // 36864 B
    unsigned short* At = smem;          // 128x32 shorts (8 KB), swizzled
    unsigned short* Bt = smem + 4096;   // 128x32 shorts (8 KB), swizzled

    const int b = blockIdx.z;
    const int m0 = blockIdx.y * 128, n0 = blockIdx.x * 128;
    const int t = threadIdx.x, w = t >> 6, lane = t & 63;
    const int l15 = lane & 15, quad = lane >> 4;
    const int wm = (w >> 1) * 64, wn = (w & 1) * 64;
    const unsigned short* Abase = wq + (size_t)m0 * NDIM;
    const unsigned short* Bbase = xnT + ((size_t)b * NPOS + n0) * NDIM;

    const int rl = lane >> 2, sl = lane & 3;
    const int cw = (sl ^ ((rl >> 1) & 3)) * 8;      // write-side global chunk offset
    const int sA = (quad ^ ((l15 >> 1) & 3)) * 8;   // read-side LDS slot offset

    f4v acc[4][4];
#pragma unroll
    for (int i = 0; i < 4; ++i)
#pragma unroll
        for (int j = 0; j < 4; ++j) { acc[i][j][0]=0.f; acc[i][j][1]=0.f; acc[i][j][2]=0.f; acc[i][j][3]=0.f; }

    for (int k0 = 0; k0 < NDIM; k0 += 32) {
        __syncthreads();                            // prev reads done
#pragma unroll
        for (int e = 0; e < 2; ++e) {
            const int seg = w * 2 + e;              // 0..7, 16 rows each
            const int r = seg * 16 + rl;
            gl_lds16(Abase + (size_t)r * NDIM + k0 + cw, At + seg * 512);
            gl_lds16(Bbase + (size_t)r * NDIM + k0 + cw, Bt + seg * 512);
        }
        __syncthreads();                            // vmcnt drain + barrier
        bf8v af[4], bfr[4];
#pragma unroll
        for (int ms = 0; ms < 4; ++ms) af[ms]  = *(const bf8v*)&At[(wm + ms * 16 + l15) * 32 + sA];
#pragma unroll
        for (int ns = 0; ns < 4; ++ns) bfr[ns] = *(const bf8v*)&Bt[(wn + ns * 16 + l15) * 32 + sA];
#pragma unroll
        for (int ms = 0; ms < 4; ++ms)
#pragma unroll
            for (int ns = 0; ns < 4; ++ns)
                acc[ms][ns] = mfma16(af[ms], bfr[ns], acc[ms][ns]);
    }
    __syncthreads();   // done with At/Bt; smem reusable as bounce

    const int sec = m0 >> 9;         // 0=q, 1=k, 2=v
    const int om  = m0 & 511;
    if (sec == 2) {
        unsigned short* vbase = vv + ((size_t)b * NDIM + om) * NPOS + n0;
#pragma unroll
        for (int ms = 0; ms < 4; ++ms)
#pragma unroll
            for (int r = 0; r < 4; ++r) {
                int m = wm + ms * 16 + quad * 4 + r;
#pragma unroll
                for (int ns = 0; ns < 4; ++ns)
                    vbase[(size_t)m * NPOS + wn + ns * 16 + l15] = f2bs(acc[ms][ns][r]);
            }
    } else {
        const float qsc = (sec == 0) ? 0.125f : 1.0f;   // fold dim_head^-0.5 into Q
        unsigned short* gT = (sec == 0 ? qT : kT) + ((size_t)b * NPOS + n0) * NDIM + om;
        unsigned short (*bw)[72] = (unsigned short(*)[72])(smem + w * 64 * 72);
#pragma unroll
        for (int ms = 0; ms < 4; ++ms)
#pragma unroll
            for (int ns = 0; ns < 4; ++ns)
#pragma unroll
                for (int r = 0; r < 4; ++r)
                    bw[ns * 16 + l15][ms * 16 + quad * 4 + r] = f2bs(acc[ms][ns][r] * qsc);
        unsigned short* dst = gT + (size_t)(wn + lane) * NDIM + wm;
#pragma unroll
        for (int q2 = 0; q2 < 8; ++q2)
            *(uint4*)(dst + q2 * 8) = *(const uint4*)&bw[lane][q2 * 8];
    }
}

// ---------------- K3: flash attention v7 (v5 structure, i-tile 64) --------
// K staged in LDS (register-prefetch pipeline); V fragments direct from
// global (consumed after QK+exp); l via constant ones B-fragment.
// 1024 blocks -> 4 blocks/CU -> 4 waves/SIMD.
__global__ __launch_bounds__(256, 4) void attn_mfma7_kernel(
    const unsigned short* __restrict__ qT, const unsigned short* __restrict__ kT,
    const unsigned short* __restrict__ vv, unsigned short* __restrict__ attnT)
{
    __shared__ unsigned short Ks[64][72];                    // [j][c]
    __shared__ __align__(16) unsigned short Ps[4][16][72];   // wave-private

    // XCD swizzle: blk&7 = h; per-XCD K/V working set 2MB < 4MB L2.
    const int blk = blockIdx.x;                 // 1024 blocks
    const int xg = blk & 7, rr = blk >> 3;
    const int i0 = (rr & 15) * 64;
    const int bh = ((rr >> 4) << 3) | xg;
    const int b = bh >> 3, h = bh & 7;

    const int t = threadIdx.x, w = t >> 6, lane = t & 63;
    const int l15 = lane & 15, quad = lane >> 4;

    const unsigned short* kbase = kT + (size_t)b * NPOS * NDIM + h * DHEAD;
    const unsigned short* vbase = vv + ((size_t)b * NDIM + h * DHEAD) * NPOS;

    // Q fragment (B-operand): wave covers 16 rows
    bf8v bq0, bq1;
    {
        const unsigned short* qrow =
            qT + ((size_t)b * NPOS + i0 + w * 16 + l15) * NDIM + h * DHEAD;
        bq0 = *(const bf8v*)(qrow + quad * 8);
        bq1 = *(const bf8v*)(qrow + 32 + quad * 8);
    }

    bf8v bones;   // constant ones fragment: l = sum_j P[i][j]
#pragma unroll
    for (int e = 0; e < 8; ++e) bones[e] = (short)0x3F80;

    // K staging indices: row t>>2, col chunk (t&3)*16
    const int jr = t >> 2, cq = (t & 3) * 16;

    // prefetch K tile 0
    uint4 ka, kb2;
    {
        const unsigned short* kp = kbase + (size_t)jr * NDIM + cq;
        ka = *(const uint4*)kp;  kb2 = *(const uint4*)(kp + 8);
    }

    f4v oc[5];
#pragma unroll
    for (int cs = 0; cs < 5; ++cs) { oc[cs][0]=0.f; oc[cs][1]=0.f; oc[cs][2]=0.f; oc[cs][3]=0.f; }

    for (int j0 = 0; j0 < NPOS; j0 += 64) {
        __syncthreads();                       // prev iter done reading Ks
        *(uint4*)&Ks[jr][cq] = ka;  *(uint4*)&Ks[jr][cq + 8] = kb2;
        __syncthreads();
        if (j0 + 64 < NPOS) {                  // prefetch next K tile under compute
            const unsigned short* kp = kbase + (size_t)(j0 + 64 + jr) * NDIM + cq;
            ka = *(const uint4*)kp;  kb2 = *(const uint4*)(kp + 8);
        }
        // V fragments for THIS tile, direct from global: issued now, consumed
        // after QK+exp -> L2 latency hidden.
        bf8v bv[4][2];
#pragma unroll
        for (int cs = 0; cs < 4; ++cs) {
            const unsigned short* vrow = vbase + (size_t)(cs * 16 + l15) * NPOS + j0;
            bv[cs][0] = *(const bf8v*)(vrow + quad * 8);
            bv[cs][1] = *(const bf8v*)(vrow + 32 + quad * 8);
        }

        // S^T[j][i]: A = K from LDS, B = Q regs; scale pre-folded into Q
#pragma unroll
        for (int jt = 0; jt < 4; ++jt) {
            bf8v ak0 = *(const bf8v*)&Ks[jt * 16 + l15][quad * 8];
            bf8v ak1 = *(const bf8v*)&Ks[jt * 16 + l15][32 + quad * 8];
            f4v s; s[0]=0.f; s[1]=0.f; s[2]=0.f; s[3]=0.f;
            s = mfma16(ak0, bq0, s);
            s = mfma16(ak1, bq1, s);
            ushort4 pu;
            pu.x = f2bs(__expf(fminf(s[0], 60.f)));
            pu.y = f2bs(__expf(fminf(s[1], 60.f)));
            pu.z = f2bs(__expf(fminf(s[2], 60.f)));
            pu.w = f2bs(__expf(fminf(s[3], 60.f)));
            *(ushort4*)&Ps[w][l15][jt * 16 + quad * 4] = pu;
        }
        // P as A-operand (same-wave LDS round trip)
        bf8v ap0 = *(const bf8v*)&Ps[w][l15][quad * 8];
        bf8v ap1 = *(const bf8v*)&Ps[w][l15][32 + quad * 8];
#pragma unroll
        for (int cs = 0; cs < 4; ++cs) {
            oc[cs] = mfma16(ap0, bv[cs][0], oc[cs]);
            oc[cs] = mfma16(ap1, bv[cs][1], oc[cs]);
        }
        oc[4] = mfma16(ap0, bones, oc[4]);
        oc[4] = mfma16(ap1, bones, oc[4]);
    }

    float inv[4];
#pragma unroll
    for (int r = 0; r < 4; ++r) inv[r] = 1.0f / oc[4][r];   // l lane-local
    unsigned short* dst =
        attnT + ((size_t)b * NPOS + i0 + w * 16) * NDIM + h * DHEAD;
#pragma unroll
    for (int cs = 0; cs < 4; ++cs)
#pragma unroll
        for (int r = 0; r < 4; ++r)
            dst[(size_t)(quad * 4 + r) * NDIM + cs * 16 + l15] = f2bs(oc[cs][r] * inv[r]);
}

// ---------------- K4: out projection (64m x 128n tiles, async staging) ----
__global__ __launch_bounds__(256) void out_mfma_kernel(
    const unsigned short* __restrict__ wo, const unsigned short* __restrict__ attnT,
    const float* __restrict__ x, float* __restrict__ outp)
{
    __shared__ __align__(16) unsigned short smem[6144];   // A 64x32 | B 128x32
    unsigned short* At = smem;            // 2048 shorts
    unsigned short* Bt = smem + 2048;     // 4096 shorts

    const int b = blockIdx.z;
    const int m0 = blockIdx.y * 64, n0 = blockIdx.x * 128;
    const int t = threadIdx.x, w = t >> 6, lane = t & 63;
    const int l15 = lane & 15, quad = lane >> 4;
    const int wm = (w >> 1) * 32, wn = (w & 1) * 64;
    const unsigned short* Abase = wo + (size_t)m0 * NDIM;
    const unsigned short* Bbase = attnT + ((size_t)b * NPOS + n0) * NDIM;

    const int rl = lane >> 2, sl = lane & 3;
    const int cw = (sl ^ ((rl >> 1) & 3)) * 8;
    const int sA = (quad ^ ((l15 >> 1) & 3)) * 8;

    f4v acc[2][4];
#pragma unroll
    for (int i = 0; i < 2; ++i)
#pragma unroll
        for (int j = 0; j < 4; ++j) { acc[i][j][0]=0.f; acc[i][j][1]=0.f; acc[i][j][2]=0.f; acc[i][j][3]=0.f; }

    for (int k0 = 0; k0 < NDIM; k0 += 32) {
        __syncthreads();
        {   // A: 64 rows, one 16-row segment per wave (1 load/thread)
            const int r = w * 16 + rl;
            gl_lds16(Abase + (size_t)r * NDIM + k0 + cw, At + w * 512);
        }
#pragma unroll
        for (int e = 0; e < 2; ++e) {   // B: 128 rows (2 loads/thread)
            const int seg = w * 2 + e;
            const int r = seg * 16 + rl;
            gl_lds16(Bbase + (size_t)r * NDIM + k0 + cw, Bt + seg * 512);
        }
        __syncthreads();
        bf8v af[2], bfr[4];
#pragma unroll
        for (int ms = 0; ms < 2; ++ms) af[ms]  = *(const bf8v*)&At[(wm + ms * 16 + l15) * 32 + sA];
#pragma unroll
        for (int ns = 0; ns < 4; ++ns) bfr[ns] = *(const bf8v*)&Bt[(wn + ns * 16 + l15) * 32 + sA];
#pragma unroll
        for (int ms = 0; ms < 2; ++ms)
#pragma unroll
            for (int ns = 0; ns < 4; ++ns)
                acc[ms][ns] = mfma16(af[ms], bfr[ns], acc[ms][ns]);
    }
    const float* xb = x + ((size_t)b * NDIM + m0) * NPOS + n0;
    float* ob = outp + ((size_t)b * NDIM + m0) * NPOS + n0;
#pragma unroll
    for (int ms = 0; ms < 2; ++ms)
#pragma unroll
        for (int r = 0; r < 4; ++r) {
            int m = wm + ms * 16 + quad * 4 + r;
#pragma unroll
            for (int ns = 0; ns < 4; ++ns) {
                int n = wn + ns * 16 + l15;
                ob[(size_t)m * NPOS + n] = acc[ms][ns][r] + xb[(size_t)m * NPOS + n];
            }
        }
}

extern "C" void kernel_launch(void* const* d_in, const int* in_sizes, int n_in,
                              void* d_out, int out_size, void* d_ws, size_t ws_size,
                              hipStream_t stream) {
    const float* x     = (const float*)d_in[0];   // [8][512][32][32] f32
    const float* gamma = (const float*)d_in[1];   // [512] f32
    const float* w_qkv = (const float*)d_in[2];   // [1536][512] f32
    const float* w_out = (const float*)d_in[3];   // [512][512] f32
    float* out = (float*)d_out;                   // [8][512][32][32] f32

    unsigned short* xnT = (unsigned short*)d_ws;             // 8*1024*512 bf16
    unsigned short* wqb = xnT + (size_t)NB * NPOS * NDIM;    // 1536*512
    unsigned short* wob = wqb + (size_t)INNER * NDIM;        // 512*512
    unsigned short* qTw = wob + (size_t)NDIM * NDIM;         // 8*1024*512
    unsigned short* kTw = qTw + (size_t)NB * NPOS * NDIM;
    unsigned short* vvw = kTw + (size_t)NB * NPOS * NDIM;
    unsigned short* aTw = vvw + (size_t)NB * NPOS * NDIM;

    ln_xnorm_kernel<<<dim3(NPOS / 64, NB), 256, 0, stream>>>(x, gamma, xnT);
    castw2_kernel<<<(INNER * NDIM + NDIM * NDIM) / 4 / 256, 256, 0, stream>>>(
        w_qkv, wqb, w_out, wob);
    qkv_mfma_kernel<<<dim3(NPOS / 128, INNER / 128, NB), 256, 0, stream>>>(
        wqb, xnT, qTw, kTw, vvw);
    attn_mfma7_kernel<<<1024, 256, 0, stream>>>(qTw, kTw, vvw, aTw);
    out_mfma_kernel<<<dim3(NPOS / 128, NDIM / 64, NB), 256, 0, stream>>>(wob, aTw, x, out);
}

// Round 11
// 151.854 us; speedup vs baseline: 1.2535x; 1.2535x over previous
//
#include <hip/hip_runtime.h>
#include <hip/hip_bf16.h>

#define NDIM   512
#define NPOS   1024   // 32*32
#define NB     8
#define INNER  1536
#define DHEAD  64

typedef __attribute__((ext_vector_type(8))) short bf8v;   // 8 bf16 = 4 VGPRs
typedef __attribute__((ext_vector_type(4))) float f4v;

__device__ __forceinline__ f4v mfma16(bf8v a, bf8v b, f4v c) {
    return __builtin_amdgcn_mfma_f32_16x16x32_bf16(a, b, c, 0, 0, 0);
}

__device__ __forceinline__ unsigned short f2bs(float v) {
    __hip_bfloat16 h = __float2bfloat16(v);   // RNE
    return *reinterpret_cast<unsigned short*>(&h);
}

// async global->LDS, 16B per lane; lds dst = wave-uniform base + lane*16
__device__ __forceinline__ void gl_lds16(const unsigned short* g, unsigned short* l) {
    __builtin_amdgcn_global_load_lds(
        (const __attribute__((address_space(1))) void*)g,
        (__attribute__((address_space(3))) void*)l,
        16, 0, 0);
}

// ---------------- K1: fused LN stats + normalize + cast + transpose -------
__global__ __launch_bounds__(256) void ln_xnorm_kernel(
    const float* __restrict__ x, const float* __restrict__ gamma,
    unsigned short* __restrict__ xnT)
{
    __shared__ float ssum[4][64];
    __shared__ float ssq[4][64];
    __shared__ float mean_s[64];
    __shared__ float rstd_s[64];
    __shared__ unsigned short tile[64][72];

    const int b = blockIdx.y;
    const int n0 = blockIdx.x * 64;
    const int t = threadIdx.x;

    {
        const int ln = t & 63, cg = t >> 6;
        const float* xp = x + (size_t)b * NDIM * NPOS + n0 + ln;
        float s = 0.f, ss = 0.f;
        for (int c = cg * 128; c < cg * 128 + 128; ++c) {
            float v = xp[(size_t)c * NPOS];
            s += v; ss += v * v;
        }
        ssum[cg][ln] = s; ssq[cg][ln] = ss;
    }
    __syncthreads();
    if (t < 64) {
        float st = ssum[0][t] + ssum[1][t] + ssum[2][t] + ssum[3][t];
        float sq = ssq[0][t] + ssq[1][t] + ssq[2][t] + ssq[3][t];
        float m = st * (1.0f / NDIM);
        float var = sq * (1.0f / NDIM) - m * m;
        mean_s[t] = m;
        rstd_s[t] = rsqrtf(var + 1e-5f);
    }
    __syncthreads();

    const int cl = t >> 2, nq = (t & 3) * 16;
    const int n = t >> 2, cq = (t & 3) * 16;
    for (int c0 = 0; c0 < NDIM; c0 += 64) {
        const float g = gamma[c0 + cl];
        const float* xp = x + ((size_t)b * NDIM + c0 + cl) * NPOS + n0 + nq;
#pragma unroll
        for (int q = 0; q < 4; ++q) {
            float4 v = *(const float4*)(xp + q * 4);
            float4 m = *(const float4*)&mean_s[nq + q * 4];
            float4 r = *(const float4*)&rstd_s[nq + q * 4];
            tile[nq + q * 4 + 0][cl] = f2bs((v.x - m.x) * r.x * g);
            tile[nq + q * 4 + 1][cl] = f2bs((v.y - m.y) * r.y * g);
            tile[nq + q * 4 + 2][cl] = f2bs((v.z - m.z) * r.z * g);
            tile[nq + q * 4 + 3][cl] = f2bs((v.w - m.w) * r.w * g);
        }
        __syncthreads();
        unsigned short* dst = xnT + ((size_t)b * NPOS + n0 + n) * NDIM + c0 + cq;
        *(uint4*)dst       = *(const uint4*)&tile[n][cq];
        *(uint4*)(dst + 8) = *(const uint4*)&tile[n][cq + 8];
        __syncthreads();
    }
}

// ---------------- K1b: f32 -> bf16 cast, both weights in one grid ---------
__global__ __launch_bounds__(256) void castw2_kernel(
    const float* __restrict__ wq, unsigned short* __restrict__ wqb,
    const float* __restrict__ wo, unsigned short* __restrict__ wob)
{
    const int n1 = INNER * NDIM / 4;
    int i = blockIdx.x * 256 + threadIdx.x;
    const float* src; unsigned short* dst; int j;
    if (i < n1) { src = wq; dst = wqb; j = i; }
    else        { src = wo; dst = wob; j = i - n1; }
    float4 v = ((const float4*)src)[j];
    ushort4 u;
    u.x = f2bs(v.x); u.y = f2bs(v.y); u.z = f2bs(v.z); u.w = f2bs(v.w);
    ((ushort4*)dst)[j] = u;
}

// ---------------- K2: QKV GEMM (MFMA bf16, async LDS staging) -------------
__global__ __launch_bounds__(256) void qkv_mfma_kernel(
    const unsigned short* __restrict__ wq, const unsigned short* __restrict__ xnT,
    unsigned short* __restrict__ qT, unsigned short* __restrict__ kT,
    unsigned short* __restrict__ vv)
{
    __shared__ __align__(16) unsigned short smem[4 * 64 * 72];  // 36864 B
    unsigned short* At = smem;          // 128x32 shorts (8 KB), swizzled
    unsigned short* Bt = smem + 4096;   // 128x32 shorts (8 KB), swizzled

    const int b = blockIdx.z;
    const int m0 = blockIdx.y * 128, n0 = blockIdx.x * 128;
    const int t = threadIdx.x, w = t >> 6, lane = t & 63;
    const int l15 = lane & 15, quad = lane >> 4;
    const int wm = (w >> 1) * 64, wn = (w & 1) * 64;
    const unsigned short* Abase = wq + (size_t)m0 * NDIM;
    const unsigned short* Bbase = xnT + ((size_t)b * NPOS + n0) * NDIM;

    const int rl = lane >> 2, sl = lane & 3;
    const int cw = (sl ^ ((rl >> 1) & 3)) * 8;      // write-side global chunk offset
    const int sA = (quad ^ ((l15 >> 1) & 3)) * 8;   // read-side LDS slot offset

    f4v acc[4][4];
#pragma unroll
    for (int i = 0; i < 4; ++i)
#pragma unroll
        for (int j = 0; j < 4; ++j) { acc[i][j][0]=0.f; acc[i][j][1]=0.f; acc[i][j][2]=0.f; acc[i][j][3]=0.f; }

    for (int k0 = 0; k0 < NDIM; k0 += 32) {
        __syncthreads();                            // prev reads done
#pragma unroll
        for (int e = 0; e < 2; ++e) {
            const int seg = w * 2 + e;              // 0..7, 16 rows each
            const int r = seg * 16 + rl;
            gl_lds16(Abase + (size_t)r * NDIM + k0 + cw, At + seg * 512);
            gl_lds16(Bbase + (size_t)r * NDIM + k0 + cw, Bt + seg * 512);
        }
        __syncthreads();                            // vmcnt drain + barrier
        bf8v af[4], bfr[4];
#pragma unroll
        for (int ms = 0; ms < 4; ++ms) af[ms]  = *(const bf8v*)&At[(wm + ms * 16 + l15) * 32 + sA];
#pragma unroll
        for (int ns = 0; ns < 4; ++ns) bfr[ns] = *(const bf8v*)&Bt[(wn + ns * 16 + l15) * 32 + sA];
#pragma unroll
        for (int ms = 0; ms < 4; ++ms)
#pragma unroll
            for (int ns = 0; ns < 4; ++ns)
                acc[ms][ns] = mfma16(af[ms], bfr[ns], acc[ms][ns]);
    }
    __syncthreads();   // done with At/Bt; smem reusable as bounce

    const int sec = m0 >> 9;         // 0=q, 1=k, 2=v
    const int om  = m0 & 511;
    if (sec == 2) {
        unsigned short* vbase = vv + ((size_t)b * NDIM + om) * NPOS + n0;
#pragma unroll
        for (int ms = 0; ms < 4; ++ms)
#pragma unroll
            for (int r = 0; r < 4; ++r) {
                int m = wm + ms * 16 + quad * 4 + r;
#pragma unroll
                for (int ns = 0; ns < 4; ++ns)
                    vbase[(size_t)m * NPOS + wn + ns * 16 + l15] = f2bs(acc[ms][ns][r]);
            }
    } else {
        const float qsc = (sec == 0) ? 0.125f : 1.0f;   // fold dim_head^-0.5 into Q
        unsigned short* gT = (sec == 0 ? qT : kT) + ((size_t)b * NPOS + n0) * NDIM + om;
        unsigned short (*bw)[72] = (unsigned short(*)[72])(smem + w * 64 * 72);
#pragma unroll
        for (int ms = 0; ms < 4; ++ms)
#pragma unroll
            for (int ns = 0; ns < 4; ++ns)
#pragma unroll
                for (int r = 0; r < 4; ++r)
                    bw[ns * 16 + l15][ms * 16 + quad * 4 + r] = f2bs(acc[ms][ns][r] * qsc);
        unsigned short* dst = gT + (size_t)(wn + lane) * NDIM + wm;
#pragma unroll
        for (int q2 = 0; q2 < 8; ++q2)
            *(uint4*)(dst + q2 * 8) = *(const uint4*)&bw[lane][q2 * 8];
    }
}

// ---------------- K3: flash attention v8 (async dbuf LDS, 1 barrier/iter) -
// K and V tiles DMA'd (global_load_lds) into double-buffered LDS one full
// j-iteration ahead; the compiler's vmcnt(0)-before-barrier drain lands one
// iter after issue -> prefetch is structural. 8-slot XOR swizzle
// (slot = chunk ^ (row&7), 128B rows) -> all b128 frag reads 2-way = free.
__global__ __launch_bounds__(256, 2) void attn_mfma8_kernel(
    const unsigned short* __restrict__ qT, const unsigned short* __restrict__ kT,
    const unsigned short* __restrict__ vv, unsigned short* __restrict__ attnT)
{
    __shared__ __align__(16) unsigned short Kb[2][4096];     // [j][c] 64x64, swizzled
    __shared__ __align__(16) unsigned short Vb[2][4096];     // [c][j] 64x64, swizzled
    __shared__ __align__(16) unsigned short Ps[4][32][72];   // wave-private stripes

    // XCD swizzle: blk&7 = h; per-XCD K/V working set 2MB < 4MB L2.
    const int blk = blockIdx.x;                 // 512 blocks
    const int xg = blk & 7, rr = blk >> 3;
    const int i0 = (rr & 7) * 128;
    const int bh = ((rr >> 3) << 3) | xg;
    const int b = bh >> 3, h = bh & 7;

    const int t = threadIdx.x, w = t >> 6, lane = t & 63;
    const int l15 = lane & 15, quad = lane >> 4;

    const unsigned short* kbase = kT + (size_t)b * NPOS * NDIM + h * DHEAD;   // row j, stride NDIM
    const unsigned short* vbase = vv + ((size_t)b * NDIM + h * DHEAD) * NPOS; // row c, stride NPOS

    // Q fragments (B-operand): wave covers 32 rows, two 16-row groups
    bf8v bq[2][2];
#pragma unroll
    for (int g = 0; g < 2; ++g) {
        const unsigned short* qrow =
            qT + ((size_t)b * NPOS + i0 + w * 32 + g * 16 + l15) * NDIM + h * DHEAD;
        bq[g][0] = *(const bf8v*)(qrow + quad * 8);
        bq[g][1] = *(const bf8v*)(qrow + 32 + quad * 8);
    }

    bf8v bones;   // constant ones fragment: l = sum_j P[i][j]
#pragma unroll
    for (int e = 0; e < 8; ++e) bones[e] = (short)0x3F80;

    // staging: per wave 2 segments each for K and V; segment = 8 rows x 128B.
    // lane -> row_local = lane>>3, LDS slot = lane&7, fetches global chunk
    // g = slot ^ (row&7) so that LDS slot s holds global chunk s ^ (row&7).
    const int rloc = lane >> 3;
    const int gch = ((lane & 7) ^ (rloc & 7)) * 8;   // global chunk offset (shorts)

    // read-side slot offsets (shorts): row&7 = l15&7
    const int sw0 = (quad ^ (l15 & 7)) * 8;          // chunks 0..3 (c/j 0..31)
    const int sw1 = ((4 + quad) ^ (l15 & 7)) * 8;    // chunks 4..7 (c/j 32..63)

    // prologue: stage tile 0 into buffer 0
#pragma unroll
    for (int e = 0; e < 2; ++e) {
        const int seg = w * 2 + e;                   // 0..7
        const int row = seg * 8 + rloc;
        gl_lds16(kbase + (size_t)row * NDIM + gch, &Kb[0][seg * 512]);
        gl_lds16(vbase + (size_t)row * NPOS + gch, &Vb[0][seg * 512]);
    }

    f4v oc[2][5];
#pragma unroll
    for (int mg = 0; mg < 2; ++mg)
#pragma unroll
        for (int cs = 0; cs < 5; ++cs) { oc[mg][cs][0]=0.f; oc[mg][cs][1]=0.f; oc[mg][cs][2]=0.f; oc[mg][cs][3]=0.f; }

#pragma unroll 2
    for (int j0 = 0; j0 < NPOS; j0 += 64) {
        const int cur = (j0 >> 6) & 1, nxt = cur ^ 1;
        __syncthreads();   // vmcnt(0) drain: tile-cur DMA (issued 1 iter ago) done;
                           // also: all waves finished reading buffer nxt (prev iter)
        if (j0 + 64 < NPOS) {   // issue DMA for NEXT tile; drained at NEXT barrier
#pragma unroll
            for (int e = 0; e < 2; ++e) {
                const int seg = w * 2 + e;
                const int row = seg * 8 + rloc;
                gl_lds16(kbase + (size_t)(j0 + 64 + row) * NDIM + gch, &Kb[nxt][seg * 512]);
                gl_lds16(vbase + (size_t)row * NPOS + j0 + 64 + gch, &Vb[nxt][seg * 512]);
            }
        }

        // S^T[j][i]: A = K from LDS (2-way-free swizzled reads), B = Q regs
#pragma unroll
        for (int jt = 0; jt < 4; ++jt) {
            const int krow = (jt * 16 + l15) * 64;
            bf8v ak0 = *(const bf8v*)&Kb[cur][krow + sw0];
            bf8v ak1 = *(const bf8v*)&Kb[cur][krow + sw1];
#pragma unroll
            for (int g = 0; g < 2; ++g) {
                f4v s; s[0]=0.f; s[1]=0.f; s[2]=0.f; s[3]=0.f;
                s = mfma16(ak0, bq[g][0], s);
                s = mfma16(ak1, bq[g][1], s);
                ushort4 pu;
                pu.x = f2bs(__expf(fminf(s[0], 60.f)));
                pu.y = f2bs(__expf(fminf(s[1], 60.f)));
                pu.z = f2bs(__expf(fminf(s[2], 60.f)));
                pu.w = f2bs(__expf(fminf(s[3], 60.f)));
                // D rows j = jt*16+quad*4+r, col i_local = g*16+l15
                *(ushort4*)&Ps[w][g * 16 + l15][jt * 16 + quad * 4] = pu;
            }
        }
        // P as A-operand (same-wave LDS round trip, lgkmcnt-ordered)
        bf8v ap[2][2];
#pragma unroll
        for (int mg = 0; mg < 2; ++mg) {
            ap[mg][0] = *(const bf8v*)&Ps[w][mg * 16 + l15][quad * 8];
            ap[mg][1] = *(const bf8v*)&Ps[w][mg * 16 + l15][32 + quad * 8];
        }
        // O[i][c] += P·V^T from LDS; ones-fragment accumulates l
#pragma unroll
        for (int cs = 0; cs < 4; ++cs) {
            const int vrow = (cs * 16 + l15) * 64;
            bf8v bv0 = *(const bf8v*)&Vb[cur][vrow + sw0];
            bf8v bv1 = *(const bf8v*)&Vb[cur][vrow + sw1];
#pragma unroll
            for (int mg = 0; mg < 2; ++mg) {
                oc[mg][cs] = mfma16(ap[mg][0], bv0, oc[mg][cs]);
                oc[mg][cs] = mfma16(ap[mg][1], bv1, oc[mg][cs]);
            }
        }
#pragma unroll
        for (int mg = 0; mg < 2; ++mg) {
            oc[mg][4] = mfma16(ap[mg][0], bones, oc[mg][4]);
            oc[mg][4] = mfma16(ap[mg][1], bones, oc[mg][4]);
        }
    }

#pragma unroll
    for (int mg = 0; mg < 2; ++mg) {
        float inv[4];
#pragma unroll
        for (int r = 0; r < 4; ++r) inv[r] = 1.0f / oc[mg][4][r];   // l lane-local
        unsigned short* dst =
            attnT + ((size_t)b * NPOS + i0 + w * 32 + mg * 16) * NDIM + h * DHEAD;
#pragma unroll
        for (int cs = 0; cs < 4; ++cs)
#pragma unroll
            for (int r = 0; r < 4; ++r)
                dst[(size_t)(quad * 4 + r) * NDIM + cs * 16 + l15] = f2bs(oc[mg][cs][r] * inv[r]);
    }
}

// ---------------- K4: out projection (64m x 128n tiles, async staging) ----
__global__ __launch_bounds__(256) void out_mfma_kernel(
    const unsigned short* __restrict__ wo, const unsigned short* __restrict__ attnT,
    const float* __restrict__ x, float* __restrict__ outp)
{
    __shared__ __align__(16) unsigned short smem[6144];   // A 64x32 | B 128x32
    unsigned short* At = smem;            // 2048 shorts
    unsigned short* Bt = smem + 2048;     // 4096 shorts

    const int b = blockIdx.z;
    const int m0 = blockIdx.y * 64, n0 = blockIdx.x * 128;
    const int t = threadIdx.x, w = t >> 6, lane = t & 63;
    const int l15 = lane & 15, quad = lane >> 4;
    const int wm = (w >> 1) * 32, wn = (w & 1) * 64;
    const unsigned short* Abase = wo + (size_t)m0 * NDIM;
    const unsigned short* Bbase = attnT + ((size_t)b * NPOS + n0) * NDIM;

    const int rl = lane >> 2, sl = lane & 3;
    const int cw = (sl ^ ((rl >> 1) & 3)) * 8;
    const int sA = (quad ^ ((l15 >> 1) & 3)) * 8;

    f4v acc[2][4];
#pragma unroll
    for (int i = 0; i < 2; ++i)
#pragma unroll
        for (int j = 0; j < 4; ++j) { acc[i][j][0]=0.f; acc[i][j][1]=0.f; acc[i][j][2]=0.f; acc[i][j][3]=0.f; }

    for (int k0 = 0; k0 < NDIM; k0 += 32) {
        __syncthreads();
        {   // A: 64 rows, one 16-row segment per wave (1 load/thread)
            const int r = w * 16 + rl;
            gl_lds16(Abase + (size_t)r * NDIM + k0 + cw, At + w * 512);
        }
#pragma unroll
        for (int e = 0; e < 2; ++e) {   // B: 128 rows (2 loads/thread)
            const int seg = w * 2 + e;
            const int r = seg * 16 + rl;
            gl_lds16(Bbase + (size_t)r * NDIM + k0 + cw, Bt + seg * 512);
        }
        __syncthreads();
        bf8v af[2], bfr[4];
#pragma unroll
        for (int ms = 0; ms < 2; ++ms) af[ms]  = *(const bf8v*)&At[(wm + ms * 16 + l15) * 32 + sA];
#pragma unroll
        for (int ns = 0; ns < 4; ++ns) bfr[ns] = *(const bf8v*)&Bt[(wn + ns * 16 + l15) * 32 + sA];
#pragma unroll
        for (int ms = 0; ms < 2; ++ms)
#pragma unroll
            for (int ns = 0; ns < 4; ++ns)
                acc[ms][ns] = mfma16(af[ms], bfr[ns], acc[ms][ns]);
    }
    const float* xb = x + ((size_t)b * NDIM + m0) * NPOS + n0;
    float* ob = outp + ((size_t)b * NDIM + m0) * NPOS + n0;
#pragma unroll
    for (int ms = 0; ms < 2; ++ms)
#pragma unroll
        for (int r = 0; r < 4; ++r) {
            int m = wm + ms * 16 + quad * 4 + r;
#pragma unroll
            for (int ns = 0; ns < 4; ++ns) {
                int n = wn + ns * 16 + l15;
                ob[(size_t)m * NPOS + n] = acc[ms][ns][r] + xb[(size_t)m * NPOS + n];
            }
        }
}

extern "C" void kernel_launch(void* const* d_in, const int* in_sizes, int n_in,
                              void* d_out, int out_size, void* d_ws, size_t ws_size,
                              hipStream_t stream) {
    const float* x     = (const float*)d_in[0];   // [8][512][32][32] f32
    const float* gamma = (const float*)d_in[1];   // [512] f32
    const float* w_qkv = (const float*)d_in[2];   // [1536][512] f32
    const float* w_out = (const float*)d_in[3];   // [512][512] f32
    float* out = (float*)d_out;                   // [8][512][32][32] f32

    unsigned short* xnT = (unsigned short*)d_ws;             // 8*1024*512 bf16
    unsigned short* wqb = xnT + (size_t)NB * NPOS * NDIM;    // 1536*512
    unsigned short* wob = wqb + (size_t)INNER * NDIM;        // 512*512
    unsigned short* qTw = wob + (size_t)NDIM * NDIM;         // 8*1024*512
    unsigned short* kTw = qTw + (size_t)NB * NPOS * NDIM;
    unsigned short* vvw = kTw + (size_t)NB * NPOS * NDIM;
    unsigned short* aTw = vvw + (size_t)NB * NPOS * NDIM;

    ln_xnorm_kernel<<<dim3(NPOS / 64, NB), 256, 0, stream>>>(x, gamma, xnT);
    castw2_kernel<<<(INNER * NDIM + NDIM * NDIM) / 4 / 256, 256, 0, stream>>>(
        w_qkv, wqb, w_out, wob);
    qkv_mfma_kernel<<<dim3(NPOS / 128, INNER / 128, NB), 256, 0, stream>>>(
        wqb, xnT, qTw, kTw, vvw);
    attn_mfma8_kernel<<<512, 256, 0, stream>>>(qTw, kTw, vvw, aTw);
    out_mfma_kernel<<<dim3(NPOS / 128, NDIM / 64, NB), 256, 0, stream>>>(wob, aTw, x, out);
}

// Round 12
// 145.957 us; speedup vs baseline: 1.3042x; 1.0404x over previous
//
#include <hip/hip_runtime.h>
#include <hip/hip_bf16.h>

#define NDIM   512
#define NPOS   1024   // 32*32
#define NB     8
#define INNER  1536
#define DHEAD  64

typedef __attribute__((ext_vector_type(8))) short bf8v;   // 8 bf16 = 4 VGPRs
typedef __attribute__((ext_vector_type(4))) float f4v;

__device__ __forceinline__ f4v mfma16(bf8v a, bf8v b, f4v c) {
    return __builtin_amdgcn_mfma_f32_16x16x32_bf16(a, b, c, 0, 0, 0);
}

__device__ __forceinline__ unsigned short f2bs(float v) {
    __hip_bfloat16 h = __float2bfloat16(v);   // RNE
    return *reinterpret_cast<unsigned short*>(&h);
}

// async global->LDS, 16B per lane; lds dst = wave-uniform base + lane*16
__device__ __forceinline__ void gl_lds16(const unsigned short* g, unsigned short* l) {
    __builtin_amdgcn_global_load_lds(
        (const __attribute__((address_space(1))) void*)g,
        (__attribute__((address_space(3))) void*)l,
        16, 0, 0);
}

// ---------------- K1: fused prep = LN+transpose (blocks 0..127) -----------
//                    + weight bf16 cast (blocks 128..1151)
__global__ __launch_bounds__(256) void prep_kernel(
    const float* __restrict__ x, const float* __restrict__ gamma,
    const float* __restrict__ wq, const float* __restrict__ wo,
    unsigned short* __restrict__ xnT, unsigned short* __restrict__ wqb,
    unsigned short* __restrict__ wob)
{
    const int blk = blockIdx.x;
    const int t = threadIdx.x;
    if (blk >= 128) {
        // ---- weight cast: 262144 float4 groups over 1024 blocks ----
        const int n1 = INNER * NDIM / 4;
        int i = (blk - 128) * 256 + t;
        const float* src; unsigned short* dst; int j;
        if (i < n1) { src = wq; dst = wqb; j = i; }
        else        { src = wo; dst = wob; j = i - n1; }
        float4 v = ((const float4*)src)[j];
        ushort4 u;
        u.x = f2bs(v.x); u.y = f2bs(v.y); u.z = f2bs(v.z); u.w = f2bs(v.w);
        ((ushort4*)dst)[j] = u;
        return;
    }
    // ---- LN stats + normalize + cast + transpose ----
    __shared__ float ssum[4][64];
    __shared__ float ssq[4][64];
    __shared__ float mean_s[64];
    __shared__ float rstd_s[64];
    __shared__ unsigned short tile[64][72];

    const int b = blk >> 4;
    const int n0 = (blk & 15) * 64;
    {
        const int ln = t & 63, cg = t >> 6;
        const float* xp = x + (size_t)b * NDIM * NPOS + n0 + ln;
        float s = 0.f, ss = 0.f;
        for (int c = cg * 128; c < cg * 128 + 128; ++c) {
            float v = xp[(size_t)c * NPOS];
            s += v; ss += v * v;
        }
        ssum[cg][ln] = s; ssq[cg][ln] = ss;
    }
    __syncthreads();
    if (t < 64) {
        float st = ssum[0][t] + ssum[1][t] + ssum[2][t] + ssum[3][t];
        float sq = ssq[0][t] + ssq[1][t] + ssq[2][t] + ssq[3][t];
        float m = st * (1.0f / NDIM);
        float var = sq * (1.0f / NDIM) - m * m;
        mean_s[t] = m;
        rstd_s[t] = rsqrtf(var + 1e-5f);
    }
    __syncthreads();

    const int cl = t >> 2, nq = (t & 3) * 16;
    const int n = t >> 2, cq = (t & 3) * 16;
    for (int c0 = 0; c0 < NDIM; c0 += 64) {
        const float g = gamma[c0 + cl];
        const float* xp = x + ((size_t)b * NDIM + c0 + cl) * NPOS + n0 + nq;
#pragma unroll
        for (int q = 0; q < 4; ++q) {
            float4 v = *(const float4*)(xp + q * 4);
            float4 m = *(const float4*)&mean_s[nq + q * 4];
            float4 r = *(const float4*)&rstd_s[nq + q * 4];
            tile[nq + q * 4 + 0][cl] = f2bs((v.x - m.x) * r.x * g);
            tile[nq + q * 4 + 1][cl] = f2bs((v.y - m.y) * r.y * g);
            tile[nq + q * 4 + 2][cl] = f2bs((v.z - m.z) * r.z * g);
            tile[nq + q * 4 + 3][cl] = f2bs((v.w - m.w) * r.w * g);
        }
        __syncthreads();
        unsigned short* dst = xnT + ((size_t)b * NPOS + n0 + n) * NDIM + c0 + cq;
        *(uint4*)dst       = *(const uint4*)&tile[n][cq];
        *(uint4*)(dst + 8) = *(const uint4*)&tile[n][cq + 8];
        __syncthreads();
    }
}

// ---------------- K2: QKV GEMM (async dbuf LDS, 1 barrier/iter) -----------
__global__ __launch_bounds__(256) void qkv_mfma_kernel(
    const unsigned short* __restrict__ wq, const unsigned short* __restrict__ xnT,
    unsigned short* __restrict__ qT, unsigned short* __restrict__ kT,
    unsigned short* __restrict__ vv)
{
    // dbuf: buf c -> A = smem + c*8192, B = smem + c*8192 + 4096 (shorts)
    __shared__ __align__(16) unsigned short smem[4 * 64 * 72];  // 36864 B >= 32KB dbuf

    const int b = blockIdx.z;
    const int m0 = blockIdx.y * 128, n0 = blockIdx.x * 128;
    const int t = threadIdx.x, w = t >> 6, lane = t & 63;
    const int l15 = lane & 15, quad = lane >> 4;
    const int wm = (w >> 1) * 64, wn = (w & 1) * 64;
    const unsigned short* Abase = wq + (size_t)m0 * NDIM;
    const unsigned short* Bbase = xnT + ((size_t)b * NPOS + n0) * NDIM;

    const int rl = lane >> 2, sl = lane & 3;
    const int cw = (sl ^ ((rl >> 1) & 3)) * 8;      // write-side global chunk offset
    const int sA = (quad ^ ((l15 >> 1) & 3)) * 8;   // read-side LDS slot offset

    f4v acc[4][4];
#pragma unroll
    for (int i = 0; i < 4; ++i)
#pragma unroll
        for (int j = 0; j < 4; ++j) { acc[i][j][0]=0.f; acc[i][j][1]=0.f; acc[i][j][2]=0.f; acc[i][j][3]=0.f; }

    // prologue: stage tile k0=0 into buffer 0
#pragma unroll
    for (int e = 0; e < 2; ++e) {
        const int seg = w * 2 + e;                  // 0..7, 16 rows each
        const int r = seg * 16 + rl;
        gl_lds16(Abase + (size_t)r * NDIM + cw, smem + seg * 512);
        gl_lds16(Bbase + (size_t)r * NDIM + cw, smem + 4096 + seg * 512);
    }

    for (int k0 = 0; k0 < NDIM; k0 += 32) {
        const int cur = (k0 >> 5) & 1;
        unsigned short* At = smem + cur * 8192;
        unsigned short* Bt = At + 4096;
        __syncthreads();   // vmcnt(0): tile-cur DMA (issued 1 iter ago) done;
                           // reads of buffer cur^1 (prev iter) also done
        if (k0 + 32 < NDIM) {   // issue DMA for NEXT tile; drained at NEXT barrier
            unsigned short* An = smem + (cur ^ 1) * 8192;
#pragma unroll
            for (int e = 0; e < 2; ++e) {
                const int seg = w * 2 + e;
                const int r = seg * 16 + rl;
                gl_lds16(Abase + (size_t)r * NDIM + k0 + 32 + cw, An + seg * 512);
                gl_lds16(Bbase + (size_t)r * NDIM + k0 + 32 + cw, An + 4096 + seg * 512);
            }
        }
        bf8v af[4], bfr[4];
#pragma unroll
        for (int ms = 0; ms < 4; ++ms) af[ms]  = *(const bf8v*)&At[(wm + ms * 16 + l15) * 32 + sA];
#pragma unroll
        for (int ns = 0; ns < 4; ++ns) bfr[ns] = *(const bf8v*)&Bt[(wn + ns * 16 + l15) * 32 + sA];
#pragma unroll
        for (int ms = 0; ms < 4; ++ms)
#pragma unroll
            for (int ns = 0; ns < 4; ++ns)
                acc[ms][ns] = mfma16(af[ms], bfr[ns], acc[ms][ns]);
    }
    __syncthreads();   // done with dbuf; smem reusable as bounce

    const int sec = m0 >> 9;         // 0=q, 1=k, 2=v
    const int om  = m0 & 511;
    if (sec == 2) {
        unsigned short* vbase = vv + ((size_t)b * NDIM + om) * NPOS + n0;
#pragma unroll
        for (int ms = 0; ms < 4; ++ms)
#pragma unroll
            for (int r = 0; r < 4; ++r) {
                int m = wm + ms * 16 + quad * 4 + r;
#pragma unroll
                for (int ns = 0; ns < 4; ++ns)
                    vbase[(size_t)m * NPOS + wn + ns * 16 + l15] = f2bs(acc[ms][ns][r]);
            }
    } else {
        const float qsc = (sec == 0) ? 0.125f : 1.0f;   // fold dim_head^-0.5 into Q
        unsigned short* gT = (sec == 0 ? qT : kT) + ((size_t)b * NPOS + n0) * NDIM + om;
        unsigned short (*bw)[72] = (unsigned short(*)[72])(smem + w * 64 * 72);
#pragma unroll
        for (int ms = 0; ms < 4; ++ms)
#pragma unroll
            for (int ns = 0; ns < 4; ++ns)
#pragma unroll
                for (int r = 0; r < 4; ++r)
                    bw[ns * 16 + l15][ms * 16 + quad * 4 + r] = f2bs(acc[ms][ns][r] * qsc);
        unsigned short* dst = gT + (size_t)(wn + lane) * NDIM + wm;
#pragma unroll
        for (int q2 = 0; q2 < 8; ++q2)
            *(uint4*)(dst + q2 * 8) = *(const uint4*)&bw[lane][q2 * 8];
    }
}

// ---------------- K3: flash attention v8 (async dbuf LDS, 1 barrier/iter) -
__global__ __launch_bounds__(256, 2) void attn_mfma8_kernel(
    const unsigned short* __restrict__ qT, const unsigned short* __restrict__ kT,
    const unsigned short* __restrict__ vv, unsigned short* __restrict__ attnT)
{
    __shared__ __align__(16) unsigned short Kb[2][4096];     // [j][c] 64x64, swizzled
    __shared__ __align__(16) unsigned short Vb[2][4096];     // [c][j] 64x64, swizzled
    __shared__ __align__(16) unsigned short Ps[4][32][72];   // wave-private stripes

    // XCD swizzle: blk&7 = h; per-XCD K/V working set 2MB < 4MB L2.
    const int blk = blockIdx.x;                 // 512 blocks
    const int xg = blk & 7, rr = blk >> 3;
    const int i0 = (rr & 7) * 128;
    const int bh = ((rr >> 3) << 3) | xg;
    const int b = bh >> 3, h = bh & 7;

    const int t = threadIdx.x, w = t >> 6, lane = t & 63;
    const int l15 = lane & 15, quad = lane >> 4;

    const unsigned short* kbase = kT + (size_t)b * NPOS * NDIM + h * DHEAD;   // row j, stride NDIM
    const unsigned short* vbase = vv + ((size_t)b * NDIM + h * DHEAD) * NPOS; // row c, stride NPOS

    bf8v bq[2][2];
#pragma unroll
    for (int g = 0; g < 2; ++g) {
        const unsigned short* qrow =
            qT + ((size_t)b * NPOS + i0 + w * 32 + g * 16 + l15) * NDIM + h * DHEAD;
        bq[g][0] = *(const bf8v*)(qrow + quad * 8);
        bq[g][1] = *(const bf8v*)(qrow + 32 + quad * 8);
    }

    bf8v bones;   // constant ones fragment: l = sum_j P[i][j]
#pragma unroll
    for (int e = 0; e < 8; ++e) bones[e] = (short)0x3F80;

    const int rloc = lane >> 3;
    const int gch = ((lane & 7) ^ (rloc & 7)) * 8;   // global chunk offset (shorts)
    const int sw0 = (quad ^ (l15 & 7)) * 8;          // chunks 0..3 (c/j 0..31)
    const int sw1 = ((4 + quad) ^ (l15 & 7)) * 8;    // chunks 4..7 (c/j 32..63)

    // prologue: stage tile 0 into buffer 0
#pragma unroll
    for (int e = 0; e < 2; ++e) {
        const int seg = w * 2 + e;                   // 0..7
        const int row = seg * 8 + rloc;
        gl_lds16(kbase + (size_t)row * NDIM + gch, &Kb[0][seg * 512]);
        gl_lds16(vbase + (size_t)row * NPOS + gch, &Vb[0][seg * 512]);
    }

    f4v oc[2][5];
#pragma unroll
    for (int mg = 0; mg < 2; ++mg)
#pragma unroll
        for (int cs = 0; cs < 5; ++cs) { oc[mg][cs][0]=0.f; oc[mg][cs][1]=0.f; oc[mg][cs][2]=0.f; oc[mg][cs][3]=0.f; }

#pragma unroll 2
    for (int j0 = 0; j0 < NPOS; j0 += 64) {
        const int cur = (j0 >> 6) & 1, nxt = cur ^ 1;
        __syncthreads();   // vmcnt(0) drain: tile-cur DMA done; reads of nxt done
        if (j0 + 64 < NPOS) {
#pragma unroll
            for (int e = 0; e < 2; ++e) {
                const int seg = w * 2 + e;
                const int row = seg * 8 + rloc;
                gl_lds16(kbase + (size_t)(j0 + 64 + row) * NDIM + gch, &Kb[nxt][seg * 512]);
                gl_lds16(vbase + (size_t)row * NPOS + j0 + 64 + gch, &Vb[nxt][seg * 512]);
            }
        }

        // S^T[j][i]: A = K from LDS (2-way-free swizzled reads), B = Q regs
#pragma unroll
        for (int jt = 0; jt < 4; ++jt) {
            const int krow = (jt * 16 + l15) * 64;
            bf8v ak0 = *(const bf8v*)&Kb[cur][krow + sw0];
            bf8v ak1 = *(const bf8v*)&Kb[cur][krow + sw1];
#pragma unroll
            for (int g = 0; g < 2; ++g) {
                f4v s; s[0]=0.f; s[1]=0.f; s[2]=0.f; s[3]=0.f;
                s = mfma16(ak0, bq[g][0], s);
                s = mfma16(ak1, bq[g][1], s);
                ushort4 pu;
                pu.x = f2bs(__expf(fminf(s[0], 60.f)));
                pu.y = f2bs(__expf(fminf(s[1], 60.f)));
                pu.z = f2bs(__expf(fminf(s[2], 60.f)));
                pu.w = f2bs(__expf(fminf(s[3], 60.f)));
                *(ushort4*)&Ps[w][g * 16 + l15][jt * 16 + quad * 4] = pu;
            }
        }
        bf8v ap[2][2];
#pragma unroll
        for (int mg = 0; mg < 2; ++mg) {
            ap[mg][0] = *(const bf8v*)&Ps[w][mg * 16 + l15][quad * 8];
            ap[mg][1] = *(const bf8v*)&Ps[w][mg * 16 + l15][32 + quad * 8];
        }
#pragma unroll
        for (int cs = 0; cs < 4; ++cs) {
            const int vrow = (cs * 16 + l15) * 64;
            bf8v bv0 = *(const bf8v*)&Vb[cur][vrow + sw0];
            bf8v bv1 = *(const bf8v*)&Vb[cur][vrow + sw1];
#pragma unroll
            for (int mg = 0; mg < 2; ++mg) {
                oc[mg][cs] = mfma16(ap[mg][0], bv0, oc[mg][cs]);
                oc[mg][cs] = mfma16(ap[mg][1], bv1, oc[mg][cs]);
            }
        }
#pragma unroll
        for (int mg = 0; mg < 2; ++mg) {
            oc[mg][4] = mfma16(ap[mg][0], bones, oc[mg][4]);
            oc[mg][4] = mfma16(ap[mg][1], bones, oc[mg][4]);
        }
    }

#pragma unroll
    for (int mg = 0; mg < 2; ++mg) {
        float inv[4];
#pragma unroll
        for (int r = 0; r < 4; ++r) inv[r] = 1.0f / oc[mg][4][r];   // l lane-local
        unsigned short* dst =
            attnT + ((size_t)b * NPOS + i0 + w * 32 + mg * 16) * NDIM + h * DHEAD;
#pragma unroll
        for (int cs = 0; cs < 4; ++cs)
#pragma unroll
            for (int r = 0; r < 4; ++r)
                dst[(size_t)(quad * 4 + r) * NDIM + cs * 16 + l15] = f2bs(oc[mg][cs][r] * inv[r]);
    }
}

// ---------------- K4: out projection (async dbuf, 1 barrier/iter) ---------
__global__ __launch_bounds__(256) void out_mfma_kernel(
    const unsigned short* __restrict__ wo, const unsigned short* __restrict__ attnT,
    const float* __restrict__ x, float* __restrict__ outp)
{
    // dbuf: buf c -> A(64x32) = smem + c*6144, B(128x32) = smem + c*6144 + 2048
    __shared__ __align__(16) unsigned short smem[12288];   // 24576 B

    const int b = blockIdx.z;
    const int m0 = blockIdx.y * 64, n0 = blockIdx.x * 128;
    const int t = threadIdx.x, w = t >> 6, lane = t & 63;
    const int l15 = lane & 15, quad = lane >> 4;
    const int wm = (w >> 1) * 32, wn = (w & 1) * 64;
    const unsigned short* Abase = wo + (size_t)m0 * NDIM;
    const unsigned short* Bbase = attnT + ((size_t)b * NPOS + n0) * NDIM;

    const int rl = lane >> 2, sl = lane & 3;
    const int cw = (sl ^ ((rl >> 1) & 3)) * 8;
    const int sA = (quad ^ ((l15 >> 1) & 3)) * 8;

    f4v acc[2][4];
#pragma unroll
    for (int i = 0; i < 2; ++i)
#pragma unroll
        for (int j = 0; j < 4; ++j) { acc[i][j][0]=0.f; acc[i][j][1]=0.f; acc[i][j][2]=0.f; acc[i][j][3]=0.f; }

    // prologue: stage tile k0=0 into buffer 0
    {
        const int r = w * 16 + rl;
        gl_lds16(Abase + (size_t)r * NDIM + cw, smem + w * 512);
#pragma unroll
        for (int e = 0; e < 2; ++e) {
            const int seg = w * 2 + e;
            const int rb = seg * 16 + rl;
            gl_lds16(Bbase + (size_t)rb * NDIM + cw, smem + 2048 + seg * 512);
        }
    }

    for (int k0 = 0; k0 < NDIM; k0 += 32) {
        const int cur = (k0 >> 5) & 1;
        unsigned short* At = smem + cur * 6144;
        unsigned short* Bt = At + 2048;
        __syncthreads();
        if (k0 + 32 < NDIM) {
            unsigned short* An = smem + (cur ^ 1) * 6144;
            const int r = w * 16 + rl;
            gl_lds16(Abase + (size_t)r * NDIM + k0 + 32 + cw, An + w * 512);
#pragma unroll
            for (int e = 0; e < 2; ++e) {
                const int seg = w * 2 + e;
                const int rb = seg * 16 + rl;
                gl_lds16(Bbase + (size_t)rb * NDIM + k0 + 32 + cw, An + 2048 + seg * 512);
            }
        }
        bf8v af[2], bfr[4];
#pragma unroll
        for (int ms = 0; ms < 2; ++ms) af[ms]  = *(const bf8v*)&At[(wm + ms * 16 + l15) * 32 + sA];
#pragma unroll
        for (int ns = 0; ns < 4; ++ns) bfr[ns] = *(const bf8v*)&Bt[(wn + ns * 16 + l15) * 32 + sA];
#pragma unroll
        for (int ms = 0; ms < 2; ++ms)
#pragma unroll
            for (int ns = 0; ns < 4; ++ns)
                acc[ms][ns] = mfma16(af[ms], bfr[ns], acc[ms][ns]);
    }
    const float* xb = x + ((size_t)b * NDIM + m0) * NPOS + n0;
    float* ob = outp + ((size_t)b * NDIM + m0) * NPOS + n0;
#pragma unroll
    for (int ms = 0; ms < 2; ++ms)
#pragma unroll
        for (int r = 0; r < 4; ++r) {
            int m = wm + ms * 16 + quad * 4 + r;
#pragma unroll
            for (int ns = 0; ns < 4; ++ns) {
                int n = wn + ns * 16 + l15;
                ob[(size_t)m * NPOS + n] = acc[ms][ns][r] + xb[(size_t)m * NPOS + n];
            }
        }
}

extern "C" void kernel_launch(void* const* d_in, const int* in_sizes, int n_in,
                              void* d_out, int out_size, void* d_ws, size_t ws_size,
                              hipStream_t stream) {
    const float* x     = (const float*)d_in[0];   // [8][512][32][32] f32
    const float* gamma = (const float*)d_in[1];   // [512] f32
    const float* w_qkv = (const float*)d_in[2];   // [1536][512] f32
    const float* w_out = (const float*)d_in[3];   // [512][512] f32
    float* out = (float*)d_out;                   // [8][512][32][32] f32

    unsigned short* xnT = (unsigned short*)d_ws;             // 8*1024*512 bf16
    unsigned short* wqb = xnT + (size_t)NB * NPOS * NDIM;    // 1536*512
    unsigned short* wob = wqb + (size_t)INNER * NDIM;        // 512*512
    unsigned short* qTw = wob + (size_t)NDIM * NDIM;         // 8*1024*512
    unsigned short* kTw = qTw + (size_t)NB * NPOS * NDIM;
    unsigned short* vvw = kTw + (size_t)NB * NPOS * NDIM;
    unsigned short* aTw = vvw + (size_t)NB * NPOS * NDIM;

    prep_kernel<<<128 + (INNER * NDIM + NDIM * NDIM) / 4 / 256, 256, 0, stream>>>(
        x, gamma, w_qkv, w_out, xnT, wqb, wob);
    qkv_mfma_kernel<<<dim3(NPOS / 128, INNER / 128, NB), 256, 0, stream>>>(
        wqb, xnT, qTw, kTw, vvw);
    attn_mfma8_kernel<<<512, 256, 0, stream>>>(qTw, kTw, vvw, aTw);
    out_mfma_kernel<<<dim3(NPOS / 128, NDIM / 64, NB), 256, 0, stream>>>(wob, aTw, x, out);
}